// Round 10
// baseline (139.969 us; speedup 1.0000x reference)
//
#include <hip/hip_runtime.h>

// CostVolume via banded-correlation MFMA (v_mfma_f32_16x16x32_f16).
// cost[b,h,w,(sh+4)*9+(sw+4)] = LeakyReLU_0.1( mean_c x1[b,h,w,c]*warped[b,h+sh,w+sw,c] )
// B=8 H=128 W=192 C=128, MD=4. Output fp32 [B,H,W,81].
//
// Round-10: PERSISTENT 3-TILE BLOCKS over the unchanged round-4 step.
// Empirical rule from R6/R7/R9: __launch_bounds__ min-waves=3 collapses
// occupancy to 21.6% (allocator inflates regs past a granule boundary ->
// 2 waves/SIMD); min-waves=4 gives the ~40% band. lb(512,4) is REQUIRED.
// R9's deep-prefetch result was confounded by lb(,3) -- not re-tested here.
//
// Change vs R4 (59.7us): grid 1536 -> 512 blocks; each block processes 3
// consecutive tiles of its XCD's image with a cross-tile software pipeline:
//   tile t, step ch2: decode tile t+1, issue its chunk-0 staging loads
//   tile t, step ch3: commit next-c0 into the just-freed LDS buffer,
//                     issue next chunk-1 + next-tile x1 c0
// -> tile t+1 starts with a warm pipeline (no cold prologue), and tile t's
// epilogue stores overlap tile t+1's loads (HBM busy at boundaries).
// Cold starts per CU: 6 -> 2. Steady state per step is byte-identical to
// R4: {barrier; WRITEB(cur^1); LOADCH(+2); cvt x1; 18 MFMA}.
// Consecutive tiles are w-adjacent (33% staging-window overlap -> L2 hits).

namespace {
constexpr int Bb = 8, Hh = 128, Ww = 192, Cn = 128;
constexpr int MDc = 4;
constexpr int TH = 8, TWT = 16;        // block tile: 8 rows x 16 px
constexpr int NTHR = 512;              // 8 waves
constexpr int RH = 16;                 // staged warped rows  (h0-4 .. h0+11)
constexpr int RPX = 24;                // staged warped px    (w0-4 .. w0+19)
constexpr int KC = 32;                 // channels per chunk
constexpr int NCH = Cn / KC;           // 4
constexpr int KQB = RPX * 16;          // 384 B per kq-plane (24 x 16B slots)
constexpr int ROWB = 4 * KQB;          // 1536 B per staged row
constexpr int BUFB = RH * ROWB;        // 24576 B per buffer
constexpr int RUNS = RH * RPX * 4;     // 1536 8-channel runs per chunk
constexpr int NIT = RUNS / NTHR;       // 3
constexpr int NTILE = 3;               // tiles per block
constexpr float NEG = 0.1f;
}

typedef __fp16 h2v   __attribute__((ext_vector_type(2)));
typedef __fp16 f16x8 __attribute__((ext_vector_type(8)));
typedef float  f32x4 __attribute__((ext_vector_type(4)));

__device__ __forceinline__ unsigned pkh2(float a, float b) {
    h2v h = __builtin_amdgcn_cvt_pkrtz(a, b);
    return __builtin_bit_cast(unsigned, h);
}

// Barrier with LDS-only drain: global prefetch loads stay in flight across it.
__device__ __forceinline__ void barrier_lgkm() {
    asm volatile("s_waitcnt lgkmcnt(0)\n\ts_barrier" ::: "memory");
}

__global__ __launch_bounds__(NTHR, 4)
void costvol_mfma(const float* __restrict__ x1,
                  const float* __restrict__ wp,
                  float* __restrict__ out)
{
    __shared__ __align__(16) unsigned char smem[2 * BUFB];   // 48 KiB

    const int tid  = threadIdx.x;
    const int wv   = tid >> 6;        // 0..7 : h-row within stripe
    const int lane = tid & 63;
    const int nI   = lane & 15;       // A-row m / B-col n lane index
    const int kq   = lane >> 4;       // 0..3 : k-group (8 channels each)

    // XCD-chunked persistent mapping: block kb -> XCD kb&7, 3 consecutive
    // tiles of that XCD's own image (192 tiles/image). Bijective over 1536.
    const int kb = blockIdx.x;
    int wg = (kb & 7) * 192 + (kb >> 3) * NTILE;

    int w0, h0, b;
    {
        int bx = wg % 12, t2 = wg / 12;
        w0 = bx * TWT; h0 = (t2 & 15) * TH; b = t2 >> 4;
    }

    // LDS offsets are tile-independent
    int l_off[NIT];
#pragma unroll
    for (int it = 0; it < NIT; ++it) {
        int s = tid + it * NTHR, skq = s & 3, t = s >> 2;
        int px = t % RPX, row = t / RPX;
        l_off[it] = row * ROWB + skq * KQB + ((px ^ (skq << 1)) * 16);
    }

    int g_off[NIT]; bool g_ok[NIT];
    auto OFFS = [&](int tw0, int th0, int tb) {
#pragma unroll
        for (int it = 0; it < NIT; ++it) {
            int s = tid + it * NTHR, skq = s & 3, t = s >> 2;
            int px = t % RPX, row = t / RPX;
            int hw = th0 - MDc + row, ww = tw0 - MDc + px;
            bool ok = (unsigned)hw < (unsigned)Hh && (unsigned)ww < (unsigned)Ww;
            g_ok[it]  = ok;
            g_off[it] = ((tb * Hh + (ok ? hw : 0)) * Ww + (ok ? ww : 0)) * Cn + skq * 8;
        }
    };
    OFFS(w0, h0, b);

    uint4 gp[NIT];
    auto LOADCH = [&](int ch) {
#pragma unroll
        for (int it = 0; it < NIT; ++it) {
            if (g_ok[it]) {
                const float* p = wp + g_off[it] + ch * KC;
                float4 u = *reinterpret_cast<const float4*>(p);
                float4 v = *reinterpret_cast<const float4*>(p + 4);
                gp[it] = make_uint4(pkh2(u.x, u.y), pkh2(u.z, u.w),
                                    pkh2(v.x, v.y), pkh2(v.z, v.w));
            } else {
                gp[it] = make_uint4(0u, 0u, 0u, 0u);
            }
        }
    };
    auto WRITEB = [&](int buf) {
#pragma unroll
        for (int it = 0; it < NIT; ++it)
            *reinterpret_cast<uint4*>(smem + buf * BUFB + l_off[it]) = gp[it];
    };

    // ---- cold prologue (first tile only) ----
    LOADCH(0);

    const float* xp = x1 + ((size_t)((b * Hh + h0 + wv) * Ww) + w0 + nI) * Cn + kq * 8;
    float4 ar_u = *reinterpret_cast<const float4*>(xp);
    float4 ar_v = *reinterpret_cast<const float4*>(xp + 4);

    f32x4 ac0[9], ac1[9];
#pragma unroll
    for (int s = 0; s < 9; ++s) {
        f32x4 z = {0.f, 0.f, 0.f, 0.f};
        ac0[s] = z; ac1[s] = z;
    }

    // per-lane B fragment offset within a staged row; tile1 = ro0 + 128
    const int ro0 = kq * KQB + ((nI ^ (kq << 1)) * 16);

    WRITEB(0); LOADCH(1);

    int nw0 = w0, nh0 = h0, nb = b;
    const float* xpn = xp;
    const float sc = 1.0f / (float)Cn;

    for (int t = 0; t < NTILE; ++t) {
        const bool hn = (t + 1 < NTILE);
#pragma unroll
        for (int ch = 0; ch < NCH; ++ch) {
            barrier_lgkm();
            // commit the chunk loaded last step; target buffer alternates
            if (ch != 3 || hn) WRITEB((ch & 1) ^ 1);
            // issue loads 2 steps ahead (chunk stream continues across tiles)
            if (ch == 0) LOADCH(2);
            if (ch == 1) LOADCH(3);
            if (ch == 2 && hn) {
                int wgn = wg + 1;
                int bx = wgn % 12, t2 = wgn / 12;
                nw0 = bx * TWT; nh0 = (t2 & 15) * TH; nb = t2 >> 4;
                OFFS(nw0, nh0, nb);           // current tile's loads all issued
                xpn = x1 + ((size_t)((nb * Hh + nh0 + wv) * Ww) + nw0 + nI) * Cn + kq * 8;
                LOADCH(0);                    // next tile chunk 0
            }
            if (ch == 3 && hn) LOADCH(1);     // next tile chunk 1
            // x1: convert this chunk (loaded last step), issue next
            uint4 afr = make_uint4(pkh2(ar_u.x, ar_u.y), pkh2(ar_u.z, ar_u.w),
                                   pkh2(ar_v.x, ar_v.y), pkh2(ar_v.z, ar_v.w));
            if (ch < 3) {
                ar_u = *reinterpret_cast<const float4*>(xp + (ch + 1) * KC);
                ar_v = *reinterpret_cast<const float4*>(xp + (ch + 1) * KC + 4);
            } else if (hn) {
                ar_u = *reinterpret_cast<const float4*>(xpn);
                ar_v = *reinterpret_cast<const float4*>(xpn + 4);
            }
            f16x8 av = __builtin_bit_cast(f16x8, afr);
            const unsigned char* base = smem + (ch & 1) * BUFB;
#pragma unroll
            for (int sh = 0; sh < 9; ++sh) {
                const unsigned char* rp = base + (wv + sh) * ROWB;
                uint4 b0 = *reinterpret_cast<const uint4*>(rp + ro0);
                uint4 b1 = *reinterpret_cast<const uint4*>(rp + ro0 + 128);
                ac0[sh] = __builtin_amdgcn_mfma_f32_16x16x32_f16(
                    av, __builtin_bit_cast(f16x8, b0), ac0[sh], 0, 0, 0);
                ac1[sh] = __builtin_amdgcn_mfma_f32_16x16x32_f16(
                    av, __builtin_bit_cast(f16x8, b1), ac1[sh], 0, 0, 0);
            }
        }

        // ---- epilogue for tile t: direct band stores (overlaps next tile's
        //      in-flight loads); coords still current (next in n-vars) ----
        const size_t rowbase = ((size_t)((b * Hh + h0 + wv) * Ww) + w0) * 81;
#pragma unroll
        for (int rg = 0; rg < 4; ++rg) {
            int m = kq * 4 + rg;
            int d = nI - m;
            bool t0 = (d >= 0 && d <= 8);
            bool t1 = (d >= -8 && d <= 0 && nI >= 8);
            size_t mb = rowbase + (size_t)m * 81;
#pragma unroll
            for (int sh = 0; sh < 9; ++sh) {
                if (t0) {
                    float v = ac0[sh][rg] * sc;
                    v = (v >= 0.f) ? v : NEG * v;
                    out[mb + sh * 9 + d] = v;
                }
                if (t1) {
                    float v = ac1[sh][rg] * sc;
                    v = (v >= 0.f) ? v : NEG * v;
                    out[mb + sh * 9 + d + 8] = v;
                }
            }
        }

        if (hn) {
#pragma unroll
            for (int s = 0; s < 9; ++s) {
                f32x4 z = {0.f, 0.f, 0.f, 0.f};
                ac0[s] = z; ac1[s] = z;
            }
            w0 = nw0; h0 = nh0; b = nb; xp = xpn; ++wg;
        }
    }
}

extern "C" void kernel_launch(void* const* d_in, const int* in_sizes, int n_in,
                              void* d_out, int out_size, void* d_ws, size_t ws_size,
                              hipStream_t stream) {
    const float* x1 = (const float*)d_in[0];
    const float* wp = (const float*)d_in[1];
    float* out = (float*)d_out;
    dim3 grid(512, 1, 1);   // 512 persistent blocks x 3 tiles, XCD-chunked
    costvol_mfma<<<grid, NTHR, 0, stream>>>(x1, wp, out);
}

// Round 11
// 55.337 us; speedup vs baseline: 2.5294x; 2.5294x over previous
//
#include <hip/hip_runtime.h>

// CostVolume via banded-correlation MFMA (v_mfma_f32_16x16x32_f16).
// cost[b,h,w,(sh+4)*9+(sw+4)] = LeakyReLU_0.1( mean_c x1[b,h,w,c]*warped[b,h+sh,w+sw,c] )
// B=8 H=128 W=192 C=128, MD=4. Output fp32 [B,H,W,81].
//
// Round-11: round-9's DEEP DUAL-SET STAGING PREFETCH, de-confounded.
// R6/R7/R9 all carried __launch_bounds__(512,3) and all collapsed to 21.6%
// occupancy (lb granule cliff); R3/R4/R5/R8 with lb(512,4) all sit ~40%.
// So R9's schedule was never actually measured. This kernel = R4 (59.7us
// best) + dual gp sets ONLY, keeping lb(512,4).
//   gpA = even chunks, gpB = odd chunks (+12 VGPR). Prologue issues c0,c1;
//   c2 issued before the loop; c3 at step0. Every chunk's load->commit
//   distance >= 1.5-2 steps and TWO 16KB bursts are in flight at all
//   times (R4: one burst, serialized per step -> measured per-CU HBM
//   2-5 GB/s vs ~25 available; Little's law says depth-2 roughly doubles
//   the overlap).
// R10 lesson: band stores must stay a tight per-tile burst (partial-line
// merge in L2); persistent multi-tile stretching caused 3.3x write amp.
// Everything else byte-identical to R4: 8x16 tile, 8 waves, RH=16
// swizzled conflict-free staging, lgkm-only barriers, XCD swizzle
// (192 wg = one image per XCD), rolling x1 prefetch, direct band stores.

namespace {
constexpr int Bb = 8, Hh = 128, Ww = 192, Cn = 128;
constexpr int MDc = 4;
constexpr int TH = 8, TWT = 16;        // block tile: 8 rows x 16 px
constexpr int NTHR = 512;              // 8 waves
constexpr int RH = 16;                 // staged warped rows  (h0-4 .. h0+11)
constexpr int RPX = 24;                // staged warped px    (w0-4 .. w0+19)
constexpr int KC = 32;                 // channels per chunk
constexpr int NCH = Cn / KC;           // 4
constexpr int KQB = RPX * 16;          // 384 B per kq-plane (24 x 16B slots)
constexpr int ROWB = 4 * KQB;          // 1536 B per staged row
constexpr int BUFB = RH * ROWB;        // 24576 B per buffer
constexpr int RUNS = RH * RPX * 4;     // 1536 8-channel runs per chunk
constexpr int NIT = RUNS / NTHR;       // 3
constexpr float NEG = 0.1f;
}

typedef __fp16 h2v   __attribute__((ext_vector_type(2)));
typedef __fp16 f16x8 __attribute__((ext_vector_type(8)));
typedef float  f32x4 __attribute__((ext_vector_type(4)));

__device__ __forceinline__ unsigned pkh2(float a, float b) {
    h2v h = __builtin_amdgcn_cvt_pkrtz(a, b);
    return __builtin_bit_cast(unsigned, h);
}

// Barrier with LDS-only drain: global prefetch loads stay in flight across it.
__device__ __forceinline__ void barrier_lgkm() {
    asm volatile("s_waitcnt lgkmcnt(0)\n\ts_barrier" ::: "memory");
}

__global__ __launch_bounds__(NTHR, 4)
void costvol_mfma(const float* __restrict__ x1,
                  const float* __restrict__ wp,
                  float* __restrict__ out)
{
    __shared__ __align__(16) unsigned char smem[2 * BUFB];   // 48 KiB

    const int tid  = threadIdx.x;
    const int wv   = tid >> 6;        // 0..7 : h-row within stripe
    const int lane = tid & 63;
    const int nI   = lane & 15;       // A-row m / B-col n lane index
    const int kq   = lane >> 4;       // 0..3 : k-group (8 channels each)

    // XCD swizzle: 1536 wg = 8 XCDs x 192; 192 = one batch image (12x16).
    const int id = blockIdx.x;
    const int wg = (id & 7) * 192 + (id >> 3);
    const int bx = wg % 12;
    const int t2 = wg / 12;
    const int by = t2 & 15;
    const int bz = t2 >> 4;

    const int w0 = bx * TWT;
    const int h0 = by * TH;
    const int b  = bz;

    // ---- warped staging decode: run = (row, px, kq), kq innermost ----
    int g_off[NIT]; int l_off[NIT]; bool g_ok[NIT];
#pragma unroll
    for (int it = 0; it < NIT; ++it) {
        int s   = tid + it * NTHR;    // 0..1535
        int skq = s & 3;
        int t   = s >> 2;             // 0..383
        int px  = t % RPX;
        int row = t / RPX;
        int hw  = h0 - MDc + row;
        int ww  = w0 - MDc + px;
        bool ok = (unsigned)hw < (unsigned)Hh && (unsigned)ww < (unsigned)Ww;
        g_ok[it]  = ok;
        g_off[it] = ((b * Hh + (ok ? hw : 0)) * Ww + (ok ? ww : 0)) * Cn + skq * 8;
        l_off[it] = row * ROWB + skq * KQB + ((px ^ (skq << 1)) * 16);
    }

    // Two independent staging register sets: A = even chunks, B = odd.
    uint4 gpA[NIT], gpB[NIT];
    auto LOADA = [&](int ch) {
#pragma unroll
        for (int it = 0; it < NIT; ++it) {
            if (g_ok[it]) {
                const float* p = wp + g_off[it] + ch * KC;
                float4 u = *reinterpret_cast<const float4*>(p);
                float4 v = *reinterpret_cast<const float4*>(p + 4);
                gpA[it] = make_uint4(pkh2(u.x, u.y), pkh2(u.z, u.w),
                                     pkh2(v.x, v.y), pkh2(v.z, v.w));
            } else {
                gpA[it] = make_uint4(0u, 0u, 0u, 0u);
            }
        }
    };
    auto LOADB = [&](int ch) {
#pragma unroll
        for (int it = 0; it < NIT; ++it) {
            if (g_ok[it]) {
                const float* p = wp + g_off[it] + ch * KC;
                float4 u = *reinterpret_cast<const float4*>(p);
                float4 v = *reinterpret_cast<const float4*>(p + 4);
                gpB[it] = make_uint4(pkh2(u.x, u.y), pkh2(u.z, u.w),
                                     pkh2(v.x, v.y), pkh2(v.z, v.w));
            } else {
                gpB[it] = make_uint4(0u, 0u, 0u, 0u);
            }
        }
    };
    auto WRITEA = [&](int buf) {
#pragma unroll
        for (int it = 0; it < NIT; ++it)
            *reinterpret_cast<uint4*>(smem + buf * BUFB + l_off[it]) = gpA[it];
    };
    auto WRITEB = [&](int buf) {
#pragma unroll
        for (int it = 0; it < NIT; ++it)
            *reinterpret_cast<uint4*>(smem + buf * BUFB + l_off[it]) = gpB[it];
    };

    // ---- prologue: issue c0,c1 back-to-back, then x1, commit c0, issue c2.
    LOADA(0);
    LOADB(1);

    const float* xp = x1 + ((size_t)((b * Hh + h0 + wv) * Ww) + w0 + nI) * Cn + kq * 8;
    float4 ar_u = *reinterpret_cast<const float4*>(xp);
    float4 ar_v = *reinterpret_cast<const float4*>(xp + 4);

    f32x4 ac0[9], ac1[9];
#pragma unroll
    for (int s = 0; s < 9; ++s) {
        f32x4 z = {0.f, 0.f, 0.f, 0.f};
        ac0[s] = z; ac1[s] = z;
    }

    // per-lane B fragment offset within a staged row; tile1 = ro0 + 128
    const int ro0 = kq * KQB + ((nI ^ (kq << 1)) * 16);

    WRITEA(0);       // commit c0 -> buf0 (waits only on gpA's loads)
    LOADA(2);        // c2 in flight across steps 0..1

    int cur = 0;
#pragma unroll
    for (int ch = 0; ch < NCH; ++ch) {
        barrier_lgkm();
        // commit chunk ch+1 into the other buffer; issue chunk ch+3
        if (ch == 0) { WRITEB(1); LOADB(3); }   // c1 -> buf1; c3 spans steps 0..2
        if (ch == 1) { WRITEA(0); }             // c2 -> buf0
        if (ch == 2) { WRITEB(1); }             // c3 -> buf1
        // x1: convert this chunk (loaded last step), issue next chunk
        uint4 afr = make_uint4(pkh2(ar_u.x, ar_u.y), pkh2(ar_u.z, ar_u.w),
                               pkh2(ar_v.x, ar_v.y), pkh2(ar_v.z, ar_v.w));
        if (ch + 1 < NCH) {
            ar_u = *reinterpret_cast<const float4*>(xp + (ch + 1) * KC);
            ar_v = *reinterpret_cast<const float4*>(xp + (ch + 1) * KC + 4);
        }
        f16x8 av = __builtin_bit_cast(f16x8, afr);
        const unsigned char* base = smem + cur * BUFB;
#pragma unroll
        for (int sh = 0; sh < 9; ++sh) {
            const unsigned char* rp = base + (wv + sh) * ROWB;   // staged row ly+sh
            uint4 b0 = *reinterpret_cast<const uint4*>(rp + ro0);
            uint4 b1 = *reinterpret_cast<const uint4*>(rp + ro0 + 128);
            ac0[sh] = __builtin_amdgcn_mfma_f32_16x16x32_f16(
                av, __builtin_bit_cast(f16x8, b0), ac0[sh], 0, 0, 0);
            ac1[sh] = __builtin_amdgcn_mfma_f32_16x16x32_f16(
                av, __builtin_bit_cast(f16x8, b1), ac1[sh], 0, 0, 0);
        }
        cur ^= 1;
    }

    // ---- direct band stores: no LDS round-trip, no barriers ----
    // C/D map: col=n=lane&15, row=m=(lane>>4)*4+reg
    // tile0: staged px p = nI      -> (m, sw4 = nI-m),   valid d=nI-m in [0,8]
    // tile1: staged px p = nI + 8  -> (m, sw4 = nI-m+8), valid d in [-8,0] && nI>=8
    // out k-index = sh*9 + sw4. Active lanes per (rg,sh,tile) write 4
    // contiguous 36B runs (one per kq) -> merged to full lines in L2.
    const float sc = 1.0f / (float)Cn;
    const size_t rowbase = ((size_t)((b * Hh + h0 + wv) * Ww) + w0) * 81;
#pragma unroll
    for (int rg = 0; rg < 4; ++rg) {
        int m = kq * 4 + rg;
        int d = nI - m;
        bool t0 = (d >= 0 && d <= 8);
        bool t1 = (d >= -8 && d <= 0 && nI >= 8);
        size_t mb = rowbase + (size_t)m * 81;
#pragma unroll
        for (int sh = 0; sh < 9; ++sh) {
            if (t0) {
                float v = ac0[sh][rg] * sc;
                v = (v >= 0.f) ? v : NEG * v;
                out[mb + sh * 9 + d] = v;
            }
            if (t1) {
                float v = ac1[sh][rg] * sc;
                v = (v >= 0.f) ? v : NEG * v;
                out[mb + sh * 9 + d + 8] = v;
            }
        }
    }
}

extern "C" void kernel_launch(void* const* d_in, const int* in_sizes, int n_in,
                              void* d_out, int out_size, void* d_ws, size_t ws_size,
                              hipStream_t stream) {
    const float* x1 = (const float*)d_in[0];
    const float* wp = (const float*)d_in[1];
    float* out = (float*)d_out;
    dim3 grid(12 * 16 * 8, 1, 1);   // 1536 blocks, XCD-swizzled in-kernel
    costvol_mfma<<<grid, NTHR, 0, stream>>>(x1, wp, out);
}